// Round 7
// baseline (2105.584 us; speedup 1.0000x reference)
//
#include <hip/hip_runtime.h>
#include <math.h>

// Problem constants (B,C,L,K) = (32, 64, 4096, 512)
#define B_DIM 32
#define C_DIM 64
#define L_DIM 4096
#define K_CB  512
#define N_ROWS (B_DIM * L_DIM)            // 131072
#define Q_ELEMS (B_DIM * C_DIM * L_DIM)   // 8388608

// Output layout (float32, concatenated in return order):
// loss(1), quantized_st(B,C,L), perplexity(1), embed(K,C), indices(B,L), encodings(N,K)
#define OFF_LOSS  0
#define OFF_Q     1
#define OFF_PERP  (1 + Q_ELEMS)
#define OFF_EMBED (OFF_PERP + 1)
#define OFF_IDX   (OFF_EMBED + K_CB * C_DIM)
#define OFF_ENC   (OFF_IDX + N_ROWS)

#define TPB     128   // threads per block (2 waves)
#define RPB     256   // rows per block (2 per thread)
#define KHALF   256   // codewords per K-half
#define KCHUNK  128   // codewords per LDS chunk (2 chunks per half)

using f4 = __attribute__((ext_vector_type(4))) float;
using f2 = __attribute__((ext_vector_type(2))) float;

// ws layout: [0:8) double loss; [16:16+2048) int hist[512]; [4096:+2048) float esq[512]

__global__ void vq_init(const float* __restrict__ embed,
                        double* __restrict__ loss_ws,
                        int* __restrict__ hist,
                        float* __restrict__ esq,
                        float* __restrict__ out_embed) {
  const int t = threadIdx.x;  // 512 threads, 1 block
  if (t == 0) *loss_ws = 0.0;
  hist[t] = 0;
  const float* row = embed + (size_t)t * C_DIM;
  float s = 0.f;
#pragma unroll
  for (int c = 0; c < C_DIM; ++c) s = fmaf(row[c], row[c], s);
  esq[t] = s;
#pragma unroll
  for (int i = 0; i < K_CB * C_DIM / 512; ++i)
    out_embed[i * 512 + t] = embed[i * 512 + t];
}

// ---------------------------------------------------------------------------
// Split-K distance GEMM. Block = (row-block rb, K-half kh): 256 rows x 256
// codewords. x in registers (f2 x 64); e broadcast from LDS (wave-uniform
// reads -> no bank traffic). Writes per-row candidate (min,idx) into the
// first 16B of the row's enc slice (scratch-in-output) and zero-fills its
// K-half of the enc matrix (nt stores overlapped under compute).
// ---------------------------------------------------------------------------
__global__ __launch_bounds__(TPB, 2) void vq_gemm(
    const float* __restrict__ in, const float* __restrict__ embed,
    const float* __restrict__ esq_g, float* __restrict__ out) {
  __shared__ float eT[KCHUNK * C_DIM];  // 32 KB, linear [k][c]
  __shared__ float esq_s[KCHUNK];

  const int tid = threadIdx.x;
  const int blk = blockIdx.x;            // 1024 blocks
  const int kh  = blk & 1;               // K-half (paired blocks share rows)
  const int rb  = blk >> 1;              // 0..511 row-block
  const int b   = rb >> 4;
  const int l0  = (rb & 15) * RPB;
  const int l   = l0 + 2 * tid;          // rows l, l+1 owned by this thread

  // --- load 2 x-rows into registers (f2, coalesced 8B/lane) ---
  const float* xp = in + (size_t)b * (C_DIM * L_DIM) + l;
  f2 x[C_DIM];
#pragma unroll
  for (int c = 0; c < C_DIM; ++c) x[c] = *(const f2*)(xp + (size_t)c * L_DIM);

  // flat_sq: sequential fmaf chain ascending c (bit-matches prior rounds)
  float fs0 = 0.f, fs1 = 0.f;
#pragma unroll
  for (int c = 0; c < C_DIM; ++c) {
    fs0 = fmaf(x[c].x, x[c].x, fs0);
    fs1 = fmaf(x[c].y, x[c].y, fs1);
  }

  f2* encb = (f2*)(out + OFF_ENC) + (size_t)rb * RPB * (K_CB / 2);
  f2 zz; zz.x = 0.f; zz.y = 0.f;

  float rmin0 = 3.402823466e38f, rmin1 = 3.402823466e38f;
  int   ridx0 = 0, ridx1 = 0;

  for (int ch = 0; ch < KHALF / KCHUNK; ++ch) {
    const int k0 = kh * KHALF + ch * KCHUNK;
    __syncthreads();  // previous chunk's readers done
    // Stage e chunk linear (coalesced f4): 8192 floats = 16 x 128thr x f4
#pragma unroll
    for (int i = 0; i < 16; ++i) {
      const int o = i * 512 + tid * 4;
      *(f4*)&eT[o] = *(const f4*)(embed + (size_t)k0 * C_DIM + o);
    }
    esq_s[tid] = esq_g[k0 + tid];
    __syncthreads();

    for (int kk = 0; kk < KCHUNK; kk += 8) {   // 16 groups of 8 codewords
      float a0[8], a1[8];
#pragma unroll
      for (int j = 0; j < 8; ++j) { a0[j] = 0.f; a1[j] = 0.f; }
#pragma unroll
      for (int cq = 0; cq < 16; ++cq) {        // c in quads, ascending
        f4 ev[8];
#pragma unroll
        for (int j = 0; j < 8; ++j)
          ev[j] = *(const f4*)&eT[(kk + j) * C_DIM + cq * 4];  // uniform -> broadcast
#pragma unroll
        for (int q = 0; q < 4; ++q) {
          const f2 xv = x[cq * 4 + q];
#pragma unroll
          for (int j = 0; j < 8; ++j) {
            a0[j] = fmaf(xv.x, ev[j][q], a0[j]);
            a1[j] = fmaf(xv.y, ev[j][q], a1[j]);
          }
        }
      }
      // enc zero-fill slice: row per sub-iter, lanes = consecutive f2 ->
      // coalesced 1KB nt-stores overlapping HBM under compute.
      {
        const int g = ch * 16 + (kk >> 3);  // 0..31
#pragma unroll
        for (int s = 0; s < 8; ++s) {
          const int row = g * 8 + s;
          if (!(kh == 0 && tid < 2))  // f2 0,1 reserved for candidates
            __builtin_nontemporal_store(
                zz, encb + (size_t)row * (K_CB / 2) + kh * (K_CB / 4) + tid);
        }
      }
      // min-update, ascending k, strict < : first-minimum semantics
#pragma unroll
      for (int j = 0; j < 8; ++j) {
        const int k = k0 + kk + j;
        const float es = esq_s[kk + j];
        const float d0 = fmaf(-2.0f, a0[j], fs0 + es);
        if (d0 < rmin0) { rmin0 = d0; ridx0 = k; }
        const float d1 = fmaf(-2.0f, a1[j], fs1 + es);
        if (d1 < rmin1) { rmin1 = d1; ridx1 = k; }
      }
    }
  }

  // --- candidate stores: f2 {min, idx} at row's enc f2-slot kh ---
  {
    f2 c0; c0.x = rmin0; c0.y = (float)ridx0;
    f2 c1; c1.x = rmin1; c1.y = (float)ridx1;
    encb[(size_t)(2 * tid)     * (K_CB / 2) + kh] = c0;
    encb[(size_t)(2 * tid + 1) * (K_CB / 2) + kh] = c1;
  }
}

// ---------------------------------------------------------------------------
// Merge candidates + idx + hist + enc-fix + quantized_st + loss.
// One thread per row (coalesced: lane = consecutive l).
// ---------------------------------------------------------------------------
__global__ __launch_bounds__(256) void vq_epilogue(
    const float* __restrict__ in, const float* __restrict__ embed,
    int* __restrict__ hist, double* __restrict__ loss_ws,
    float* __restrict__ out) {
  __shared__ double red[256];
  const int tid = threadIdx.x;
  const int r = blockIdx.x * 256 + tid;  // 0..131071 (== b*L + l)
  const int b = r >> 12;
  const int l = r & (L_DIM - 1);

  float* encrow = out + OFF_ENC + (size_t)r * K_CB;
  const f2 ca = ((const f2*)encrow)[0];  // {d_half0, k_half0}
  const f2 cb = ((const f2*)encrow)[1];  // {d_half1, k_half1}
  // strict <: half0 (lower k) wins ties -> global first-minimum
  const int k = (cb.x < ca.x) ? (int)cb.y : (int)ca.y;

  out[OFF_IDX + r] = (float)k;
  atomicAdd(&hist[k], 1);

  // fix enc scratch slots, then set the one-hot (same-address order is
  // per-thread program order, so k<4 is safe)
  f2 zz; zz.x = 0.f; zz.y = 0.f;
  ((f2*)encrow)[0] = zz;
  ((f2*)encrow)[1] = zz;
  encrow[k] = 1.0f;

  // quantized_st + loss
  const float* ep = embed + (size_t)k * C_DIM;   // L1/L2-resident gather
  const float* xp = in + (size_t)b * (C_DIM * L_DIM) + l;
  float* qp = out + OFF_Q + (size_t)b * (C_DIM * L_DIM) + l;
  double ls = 0.0;
#pragma unroll
  for (int c = 0; c < C_DIM; ++c) {
    const float xv = xp[(size_t)c * L_DIM];
    const float d = ep[c] - xv;                  // fp32, as reference
    __builtin_nontemporal_store(xv + d, qp + (size_t)c * L_DIM);
    ls += (double)(d * d);
  }

  red[tid] = ls;
  __syncthreads();
  for (int s = 128; s; s >>= 1) {
    if (tid < s) red[tid] += red[tid + s];
    __syncthreads();
  }
  if (tid == 0) atomicAdd(loss_ws, red[0]);
}

__global__ void vq_final(const int* __restrict__ hist, const double* __restrict__ loss_ws,
                         float* __restrict__ out) {
  __shared__ float red[512];
  const int t = threadIdx.x;
  const float p = (float)hist[t] * (1.0f / (float)N_ROWS);
  red[t] = p * logf(p + 1e-10f);
  __syncthreads();
  for (int s = 256; s; s >>= 1) {
    if (t < s) red[t] += red[t + s];
    __syncthreads();
  }
  if (t == 0) {
    out[OFF_PERP] = expf(-red[0]);
    const float m = (float)(*loss_ws / (double)Q_ELEMS);
    out[OFF_LOSS] = m + 0.25f * m;
  }
}

extern "C" void kernel_launch(void* const* d_in, const int* in_sizes, int n_in,
                              void* d_out, int out_size, void* d_ws, size_t ws_size,
                              hipStream_t stream) {
  (void)in_sizes; (void)n_in; (void)out_size; (void)ws_size;
  const float* in    = (const float*)d_in[0];
  const float* embed = (const float*)d_in[1];
  float* out = (float*)d_out;

  double* loss_ws = (double*)d_ws;
  int*    hist    = (int*)((char*)d_ws + 16);
  float*  esq     = (float*)((char*)d_ws + 4096);

  vq_init<<<1, 512, 0, stream>>>(embed, loss_ws, hist, esq, out + OFF_EMBED);
  vq_gemm<<<(N_ROWS / RPB) * 2, TPB, 0, stream>>>(in, embed, esq, out);
  vq_epilogue<<<N_ROWS / 256, 256, 0, stream>>>(in, embed, hist, loss_ws, out);
  vq_final<<<1, 512, 0, stream>>>(hist, loss_ws, out);
}

// Round 8
// 242.955 us; speedup vs baseline: 8.6666x; 8.6666x over previous
//
#include <hip/hip_runtime.h>
#include <math.h>

// Problem constants (B,C,L,K) = (32, 64, 4096, 512)
#define B_DIM 32
#define C_DIM 64
#define L_DIM 4096
#define K_CB  512
#define N_ROWS (B_DIM * L_DIM)            // 131072
#define Q_ELEMS (B_DIM * C_DIM * L_DIM)   // 8388608

// Output layout (float32, concatenated in return order):
// loss(1), quantized_st(B,C,L), perplexity(1), embed(K,C), indices(B,L), encodings(N,K)
#define OFF_LOSS  0
#define OFF_Q     1
#define OFF_PERP  (1 + Q_ELEMS)
#define OFF_EMBED (OFF_PERP + 1)
#define OFF_IDX   (OFF_EMBED + K_CB * C_DIM)
#define OFF_ENC   (OFF_IDX + N_ROWS)

#define TPB 256   // threads per block (4 waves); each thread owns 2 codewords
#define TM  128   // rows per block
#define XPAD 68   // xT row stride: 68 floats = 272 B (16B-aligned, bank-rotating)

using f4 = __attribute__((ext_vector_type(4))) float;
using f2 = __attribute__((ext_vector_type(2))) float;

// ws layout: [0:8) double loss; [16:16+2048) int hist[512]; [4096:+2048) float esq[512]

__global__ void vq_init(const float* __restrict__ embed,
                        double* __restrict__ loss_ws,
                        int* __restrict__ hist,
                        float* __restrict__ esq,
                        float* __restrict__ out_embed) {
  const int t = threadIdx.x;  // 512 threads, 1 block
  if (t == 0) *loss_ws = 0.0;
  hist[t] = 0;
  const float* row = embed + (size_t)t * C_DIM;
  float s = 0.f;
#pragma unroll
  for (int c = 0; c < C_DIM; ++c) s = fmaf(row[c], row[c], s);
  esq[t] = s;
#pragma unroll
  for (int i = 0; i < K_CB * C_DIM / 512; ++i)
    out_embed[i * 512 + t] = embed[i * 512 + t];
}

// ---------------------------------------------------------------------------
// Fused VQ. Thread t owns codewords (2t, 2t+1) in registers (32 f4, static
// indexing). x tile in LDS, read per row with WAVE-UNIFORM b128 broadcasts.
// Per row: 128 fma + 16 ds -> fma-issue-bound. Argmin per row: fminf
// butterfly + ballot/ffsll (lowest lane = lowest cw = exact first-min).
// enc zero-fill overlapped in the row loop; one-hot after vmcnt(0)+barrier.
// ---------------------------------------------------------------------------
__global__ __launch_bounds__(TPB) void vq_fused(
    const float* __restrict__ in, const float* __restrict__ embed,
    const float* __restrict__ esq_g, int* __restrict__ hist,
    double* __restrict__ loss_ws, float* __restrict__ out) {
  __shared__ __align__(16) float xT[TM][XPAD];  // ~34.8 KB, [row][c]
  __shared__ float  fs_s[TM];
  __shared__ f2     part[TM][4];                // per-wave {min,idx}
  __shared__ int    k_s[TM];
  __shared__ double red[TPB];

  const int tid = threadIdx.x;
  const int blk = blockIdx.x;            // 1024 blocks
  const int R0  = blk * TM;              // global flat row base (== b*L + l0)
  const int b   = blk >> 5;
  const int l0  = (blk & 31) * TM;

  // --- stage x tile: in[b][c][l0+r] -> xT[r][c] (coalesced reads) ---
  {
    const float* xb = in + (size_t)b * (C_DIM * L_DIM) + l0;
#pragma unroll
    for (int i = 0; i < 32; ++i) {
      const int flat = i * TPB + tid;    // 0..8191
      const int r = flat & (TM - 1);
      const int c = flat >> 7;
      xT[r][c] = xb[(size_t)c * L_DIM + r];
    }
  }

  // --- own 2 codewords in registers (static-indexed f4 arrays) ---
  const int cw0 = 2 * tid, cw1 = 2 * tid + 1;
  f4 e0[16], e1[16];
#pragma unroll
  for (int q = 0; q < 16; ++q) {
    e0[q] = *(const f4*)(embed + (size_t)cw0 * C_DIM + 4 * q);
    e1[q] = *(const f4*)(embed + (size_t)cw1 * C_DIM + 4 * q);
  }
  const float esq0 = esq_g[cw0];
  const float esq1 = esq_g[cw1];

  __syncthreads();  // xT visible

  // flat_sq per row: sequential fmaf chain ascending c (bit-matches np)
  if (tid < TM) {
    float s = 0.f;
#pragma unroll
    for (int c = 0; c < C_DIM; ++c) { const float v = xT[tid][c]; s = fmaf(v, v, s); }
    fs_s[tid] = s;
  }
  __syncthreads();

  const int wv = tid >> 6;   // wave id: owns cw [128*wv, 128*wv+128)
  const int ln = tid & 63;
  f2* encb = (f2*)(out + OFF_ENC) + (size_t)R0 * (K_CB / 2);
  f2 zz; zz.x = 0.f; zz.y = 0.f;

  // --- row loop: dot(x_r, e) via broadcast reads; per-row wave argmin ---
  for (int r = 0; r < TM; ++r) {
    const f4* xr = (const f4*)&xT[r][0];
    float a0 = 0.f, a1 = 0.f;
#pragma unroll
    for (int q = 0; q < 16; ++q) {
      const f4 xq = xr[q];               // wave-uniform b128 -> broadcast
#pragma unroll
      for (int i = 0; i < 4; ++i) {
        a0 = fmaf(xq[i], e0[q][i], a0);  // c ascending: q*4+i
        a1 = fmaf(xq[i], e1[q][i], a1);
      }
    }
    const float fsr = fs_s[r];
    const float d0 = fmaf(-2.0f, a0, fsr + esq0);
    const float d1 = fmaf(-2.0f, a1, fsr + esq1);
    float md; int mk;
    if (d1 < d0) { md = d1; mk = cw1; } else { md = d0; mk = cw0; }  // ties: lower k

    // wave min (exact value), then lowest lane holding it -> lowest cw
    float dm = md;
#pragma unroll
    for (int off = 32; off; off >>= 1) dm = fminf(dm, __shfl_xor(dm, off));
    const unsigned long long m = __ballot(md == dm);
    const int src = __ffsll(m) - 1;
    const int kk  = __shfl(mk, src);
    if (ln == 0) { f2 p; p.x = dm; p.y = (float)kk; part[r][wv] = p; }

    // enc zero-fill for row r (256 f2 = all 512 cols), overlaps under compute
    __builtin_nontemporal_store(zz, encb + (size_t)r * (K_CB / 2) + tid);
  }
  __syncthreads();

  // --- cross-wave merge (ascending wave = ascending cw; strict <) ---
  if (tid < TM) {
    f2 p = part[tid][0];
    float bd = p.x; int bk = (int)p.y;
#pragma unroll
    for (int w = 1; w < 4; ++w) {
      const f2 q = part[tid][w];
      if (q.x < bd) { bd = q.x; bk = (int)q.y; }
    }
    k_s[tid] = bk;
    out[OFF_IDX + R0 + tid] = (float)bk;
    atomicAdd(&hist[bk], 1);
  }

  // --- one-hot: after all zero stores of this block are complete ---
  asm volatile("s_waitcnt vmcnt(0)" ::: "memory");
  __syncthreads();
  if (tid < TM)
    out[OFF_ENC + (size_t)(R0 + tid) * K_CB + k_s[tid]] = 1.0f;

  // --- quantized_st + loss (xT reuse; embed gather is L2-resident) ---
  double ls = 0.0;
  {
    float* qb = out + OFF_Q + (size_t)b * (C_DIM * L_DIM) + l0;
#pragma unroll 4
    for (int it = 0; it < 32; ++it) {
      const int flat = it * TPB + tid;
      const int r = flat & (TM - 1);     // lane-consecutive -> coalesced store
      const int c = flat >> 7;
      const float x = xT[r][c];
      const float q = embed[(size_t)k_s[r] * C_DIM + c];
      const float d = q - x;             // fp32, as reference
      __builtin_nontemporal_store(x + d, qb + (size_t)c * L_DIM + r);
      ls += (double)(d * d);
    }
  }

  red[tid] = ls;
  __syncthreads();
  for (int s = 128; s; s >>= 1) {
    if (tid < s) red[tid] += red[tid + s];
    __syncthreads();
  }
  if (tid == 0) atomicAdd(loss_ws, red[0]);
}

__global__ void vq_final(const int* __restrict__ hist, const double* __restrict__ loss_ws,
                         float* __restrict__ out) {
  __shared__ float red[512];
  const int t = threadIdx.x;
  const float p = (float)hist[t] * (1.0f / (float)N_ROWS);
  red[t] = p * logf(p + 1e-10f);
  __syncthreads();
  for (int s = 256; s; s >>= 1) {
    if (t < s) red[t] += red[t + s];
    __syncthreads();
  }
  if (t == 0) {
    out[OFF_PERP] = expf(-red[0]);
    const float m = (float)(*loss_ws / (double)Q_ELEMS);
    out[OFF_LOSS] = m + 0.25f * m;
  }
}

extern "C" void kernel_launch(void* const* d_in, const int* in_sizes, int n_in,
                              void* d_out, int out_size, void* d_ws, size_t ws_size,
                              hipStream_t stream) {
  (void)in_sizes; (void)n_in; (void)out_size; (void)ws_size;
  const float* in    = (const float*)d_in[0];
  const float* embed = (const float*)d_in[1];
  float* out = (float*)d_out;

  double* loss_ws = (double*)d_ws;
  int*    hist    = (int*)((char*)d_ws + 16);
  float*  esq     = (float*)((char*)d_ws + 4096);

  vq_init<<<1, 512, 0, stream>>>(embed, loss_ws, hist, esq, out + OFF_EMBED);
  vq_fused<<<N_ROWS / TM, TPB, 0, stream>>>(in, embed, esq, hist, loss_ws, out);
  vq_final<<<1, 512, 0, stream>>>(hist, loss_ws, out);
}